// Round 18
// baseline (261.327 us; speedup 1.0000x reference)
//
#include <hip/hip_runtime.h>
#include <hip/hip_bf16.h>

// STSA R18: R17 + (1) route[] neighbor ids hoisted to registers before the
// chunk loop (removes a dependent global load from each chunk's gather chain),
// (2) __launch_bounds__(256,4): LDS 36864*4 = 147KB < 160KB so 4 blocks/CU fit;
// VGPR 84 <= 128 cap at 4 waves/SIMD -> +33% resident waves for latency hiding.
//  k_prep    : weights -> bf16.
//  k_fused_t : per (b,m): x->regs(af); s_q/s_k/s_v staged -> coalesced stores;
//              t_q/t_k/t_v -> LDS; temporal attn; normalized O_t -> ot.
//  k_attn_s  : 1024 blocks x 4 waves; wave = (bm, head-pair). Per-wave 9216B:
//              K [64 key][4x16B xor-slots] @0, V [64 key][80B rows] @4096.
//              4 neighbor-chunks, reg prefetch, ROLLED chunk loop (unrolling
//              triggered R8-R10 scratch-spill), no mid-loop barriers.
//              Tail: hoist at-fragments, stage O_s into K region (stride 64),
//              barrier, dual out-proj + bias -> direct out store.
// Softmax scale folded into Q (0.25*log2e*0.5; 0.5 compensates hd=16 dup
// into both K-halves), exp2, no max-subtract, normalize at the end.

typedef __attribute__((ext_vector_type(8))) short bf16x8;
typedef __attribute__((ext_vector_type(4))) short short4v;
typedef __attribute__((ext_vector_type(4))) float f32x4;

#define DEVI static __device__ __forceinline__
#define MFMA(a, b, c) __builtin_amdgcn_mfma_f32_16x16x32_bf16(a, b, c, 0, 0, 0)

static constexpr float QSCALE = 0.25f * 1.44269504088896340736f * 0.5f;

DEVI short f2bfs(float f) {
  __hip_bfloat16 h = __float2bfloat16(f);
  return __builtin_bit_cast(short, h);
}

// 64 rows x 128 bf16 LDS tile, 256B rows, XOR swizzle on write AND read.
DEVI int swzb(int row, int colh) {
  return (row * 256 + colh * 2) ^ ((row & 7) << 4);
}

// ---------------------------------------------------------------- k_prep ----
__global__ void __launch_bounds__(256) k_prep(
    const float* __restrict__ twin, const float* __restrict__ tbin,
    const float* __restrict__ twout, const float* __restrict__ tbout,
    const float* __restrict__ swin, const float* __restrict__ sbin,
    const float* __restrict__ swout, const float* __restrict__ sbout,
    short* __restrict__ wcat, float* __restrict__ biasin,
    short* __restrict__ wto, short* __restrict__ wso, float* __restrict__ biasc) {
  const int stride = gridDim.x * 256;
  const int t0 = blockIdx.x * 256 + threadIdx.x;
  for (int i = t0; i < 768 * 128; i += stride) {
    float v = (i < 384 * 128) ? twin[i] : swin[i - 384 * 128];
    wcat[i] = f2bfs(v);
  }
  for (int i = t0; i < 128 * 128; i += stride) {
    wto[i] = f2bfs(twout[i]);
    wso[i] = f2bfs(swout[i]);
  }
  for (int i = t0; i < 768; i += stride)
    biasin[i] = (i < 384) ? tbin[i] : sbin[i - 384];
  for (int i = t0; i < 128; i += stride)
    biasc[i] = tbout[i] + sbout[i];
}

// --------------------------------------------------------------- helpers ----
DEVI void attn_block(const char* qbuf, const char* kbuf, const char* vbuf,
                     int w, int lo, int hi, int colq,
                     f32x4 (*o)[4], float (*ls)[4]) {
  const f32x4 zf = {0.f, 0.f, 0.f, 0.f};
#pragma unroll
  for (int hh = 0; hh < 2; ++hh) {
    const int hc = (2 * w + hh) * 16;
    bf16x8 qf[4];
#pragma unroll
    for (int qt = 0; qt < 4; ++qt)
      qf[qt] = *(const bf16x8*)(qbuf + swzb(16 * qt + lo, hc + colq));
#pragma unroll
    for (int kc = 0; kc < 2; ++kc) {
      bf16x8 kf0 = *(const bf16x8*)(kbuf + swzb(16 * (2 * kc) + lo, hc + colq));
      bf16x8 kf1 = *(const bf16x8*)(kbuf + swzb(16 * (2 * kc + 1) + lo, hc + colq));
      f32x4 st0[4], st1[4];
#pragma unroll
      for (int qt = 0; qt < 4; ++qt) {
        st0[qt] = MFMA(kf0, qf[qt], zf);
        st1[qt] = MFMA(kf1, qf[qt], zf);
      }
#pragma unroll
      for (int qt = 0; qt < 4; ++qt)
#pragma unroll
        for (int r = 0; r < 4; ++r) {
          float p0 = exp2f(st0[qt][r]);
          float p1 = exp2f(st1[qt][r]);
          st0[qt][r] = p0; st1[qt][r] = p1;
          ls[hh][qt] += p0 + p1;
        }
      bf16x8 vf;
#pragma unroll
      for (int i = 0; i < 8; ++i) {
        int key = 32 * kc + 16 * (i >> 2) + 4 * hi + (i & 3);
        vf[i] = *(const short*)(vbuf + swzb(key, hc + lo));
      }
#pragma unroll
      for (int qt = 0; qt < 4; ++qt) {
        bf16x8 pa;
#pragma unroll
        for (int r = 0; r < 4; ++r) {
          pa[r] = f2bfs(st0[qt][r]);
          pa[4 + r] = f2bfs(st1[qt][r]);
        }
        o[hh][qt] = MFMA(pa, vf, o[hh][qt]);
      }
    }
  }
}

// -------------------------------------------------------------- k_fused_t ----
__global__ void __launch_bounds__(256) k_fused_t(
    const float* __restrict__ x, const short* __restrict__ wcat,
    const float* __restrict__ biasin,
    short* __restrict__ sq, short* __restrict__ sk, short* __restrict__ sv,
    uint4* __restrict__ ot) {
  __shared__ uint4 smv[3072];  // 48 KiB
  char* bufX = (char*)smv;     // x -> t_v
  char* bufQ = bufX + 16384;   // s-proj staging -> t_q -> O_t stage
  char* bufK = bufX + 32768;   // t_k
  const int bm = (blockIdx.x & 7) * 128 + (blockIdx.x >> 3);  // XCD-chunked
  const int b = bm >> 8, m = bm & 255;
  const int tid = threadIdx.x;

#pragma unroll
  for (int it = 0; it < 8; ++it) {
    int li = it * 256 + tid;
    int row = li >> 5, c4 = li & 31;
    float4 v = reinterpret_cast<const float4*>(x)[(size_t)((b * 64 + row) * 256 + m) * 32 + c4];
    short4v s;
    s[0] = f2bfs(v.x); s[1] = f2bfs(v.y); s[2] = f2bfs(v.z); s[3] = f2bfs(v.w);
    *(short4v*)(bufX + swzb(row, c4 * 4)) = s;
  }
  __syncthreads();

  const int w = tid >> 6, lane = tid & 63, lo = lane & 15, hi = lane >> 4;
  const int colq = 8 * (hi & 1);
  const f32x4 zf = {0.f, 0.f, 0.f, 0.f};

  bf16x8 af[4][4];
#pragma unroll
  for (int kc = 0; kc < 4; ++kc)
#pragma unroll
    for (int rt = 0; rt < 4; ++rt)
      af[kc][rt] = *(const bf16x8*)(bufX + swzb(16 * rt + lo, 32 * kc + 8 * hi));
  __syncthreads();

  // ---- s-projections FIRST (p = 3,4,5), staged through bufQ, coalesced store
#pragma unroll
  for (int p = 3; p < 6; ++p) {
#pragma unroll
    for (int j = 0; j < 2; ++j) {
      int ct = 2 * w + j;
      f32x4 a4[4] = {zf, zf, zf, zf};
#pragma unroll
      for (int kc = 0; kc < 4; ++kc) {
        bf16x8 bcol = *(const bf16x8*)(wcat + (p * 128 + 16 * ct + lo) * 128 + 32 * kc + 8 * hi);
#pragma unroll
        for (int rt = 0; rt < 4; ++rt) a4[rt] = MFMA(af[kc][rt], bcol, a4[rt]);
      }
      float bb = biasin[p * 128 + 16 * ct + lo];
      if (p == 3) {
#pragma unroll
        for (int rt = 0; rt < 4; ++rt)
#pragma unroll
          for (int r = 0; r < 4; ++r)
            *(short*)(bufQ + (16 * rt + 4 * hi + r) * 256 + (16 * ct + lo) * 2) =
                f2bfs((a4[rt][r] + bb) * QSCALE);
      } else {
        char* base = bufQ + (ct >> 1) * 4096;
        int qe = ((ct & 1) * 2 + (lo >> 3)) * 8 + (lo & 7);
#pragma unroll
        for (int rt = 0; rt < 4; ++rt)
#pragma unroll
          for (int r = 0; r < 4; ++r)
            *(short*)(base + (16 * rt + 4 * hi + r) * 64 + qe * 2) =
                f2bfs(a4[rt][r] + bb);
      }
    }
    __syncthreads();
    if (p == 3) {
#pragma unroll
      for (int it2 = 0; it2 < 4; ++it2) {
        int li = it2 * 256 + tid;
        ((uint4*)sq)[(size_t)bm * 1024 + li] = *(const uint4*)(bufQ + li * 16);
      }
    } else {
      short* dst = (p == 4) ? sk : sv;
#pragma unroll
      for (int wq = 0; wq < 4; ++wq)
        ((uint4*)dst)[((size_t)(wq * 1024 + bm)) * 256 + tid] =
            *(const uint4*)(bufQ + wq * 4096 + tid * 16);
    }
    __syncthreads();
  }

  // ---- t-projections (p = 0,1,2) -> LDS (swizzled)
#pragma unroll
  for (int p = 0; p < 3; ++p) {
#pragma unroll
    for (int j = 0; j < 2; ++j) {
      int ct = 2 * w + j;
      f32x4 a4[4] = {zf, zf, zf, zf};
#pragma unroll
      for (int kc = 0; kc < 4; ++kc) {
        bf16x8 bcol = *(const bf16x8*)(wcat + (p * 128 + 16 * ct + lo) * 128 + 32 * kc + 8 * hi);
#pragma unroll
        for (int rt = 0; rt < 4; ++rt) a4[rt] = MFMA(af[kc][rt], bcol, a4[rt]);
      }
      float bb = biasin[p * 128 + 16 * ct + lo];
      char* pb = (p == 0) ? bufQ : (p == 1) ? bufK : bufX;
      float sc = (p == 0) ? QSCALE : 1.0f;
#pragma unroll
      for (int rt = 0; rt < 4; ++rt)
#pragma unroll
        for (int r = 0; r < 4; ++r)
          *(short*)(pb + swzb(16 * rt + 4 * hi + r, 16 * ct + lo)) =
              f2bfs((a4[rt][r] + bb) * sc);
    }
  }
  __syncthreads();

  f32x4 o_t[2][4];
  float ls_t[2][4];
#pragma unroll
  for (int hh = 0; hh < 2; ++hh)
#pragma unroll
    for (int qt = 0; qt < 4; ++qt) { o_t[hh][qt] = zf; ls_t[hh][qt] = 0.f; }
  attn_block(bufQ, bufK, bufX, w, lo, hi, colq, o_t, ls_t);
  __syncthreads();

#pragma unroll
  for (int hh = 0; hh < 2; ++hh) {
    const int hc = (2 * w + hh) * 16;
#pragma unroll
    for (int qt = 0; qt < 4; ++qt) {
      float l = ls_t[hh][qt];
      l += __shfl_xor(l, 16);
      l += __shfl_xor(l, 32);
      float linv = 1.0f / l;
#pragma unroll
      for (int r = 0; r < 4; ++r) {
        float lr = __shfl(linv, 4 * hi + r);
        *(short*)(bufQ + swzb(16 * qt + 4 * hi + r, hc + lo)) = f2bfs(o_t[hh][qt][r] * lr);
      }
    }
  }
  __syncthreads();
#pragma unroll
  for (int it = 0; it < 4; ++it) {
    int li = it * 256 + tid;
    ot[(size_t)bm * 1024 + li] = *(const uint4*)(bufQ + swzb(li >> 4, (li & 15) * 8));
  }
}

// --------------------------------------------------------------- k_attn_s ----
// R17 structure + hoisted route + launch_bounds(256,4).
__global__ void __launch_bounds__(256, 4) k_attn_s(
    const short* __restrict__ sq, const short* __restrict__ skp,
    const short* __restrict__ svp, const int* __restrict__ route,
    const short* __restrict__ ot, const short* __restrict__ wto,
    const short* __restrict__ wso, const float* __restrict__ biasc,
    float* __restrict__ out) {
  __shared__ char smem[36864];  // 4 x 9216; 4 blocks/CU fit (147K < 160K)
  const int bm = (blockIdx.x & 7) * 128 + (blockIdx.x >> 3);  // XCD-chunked
  const int b = bm >> 8, m = bm & 255;
  const int tid = threadIdx.x;
  const int w = tid >> 6, l = tid & 63;
  const int lo = l & 15, hi = l >> 4, hi1 = hi & 1;
  const int xr = (l & 3) ^ ((l >> 2) & 3);             // reader xor (f(lo))
  const int sw = (l & 3) ^ ((l >> 2) & 3) ^ (l >> 4);  // writer slot q^xr(kk)
  char* kbase = smem + w * 9216;
  char* vbase = kbase + 4096;
  const uint4* skp4 = (const uint4*)skp;
  const uint4* svp4 = (const uint4*)svp;
  const f32x4 zf = {0.f, 0.f, 0.f, 0.f};

  // hoist neighbor ids: gather chains no longer wait on route loads
  const int rn0 = route[m * 4 + 0], rn1 = route[m * 4 + 1];
  const int rn2 = route[m * 4 + 2], rn3 = route[m * 4 + 3];

  // Q fragments (this head-pair's 32-dim slice), loaded once from global
  bf16x8 qf[2][4];
#pragma unroll
  for (int hh = 0; hh < 2; ++hh)
#pragma unroll
    for (int qt = 0; qt < 4; ++qt)
      qf[hh][qt] = *(const bf16x8*)(sq + (size_t)(bm * 64 + 16 * qt + lo) * 128 +
                                    w * 32 + hh * 16 + 8 * hi1);

  uint4 pk[4], pv[4];
  int nb = rn0;

#define ISSUE()                                                            \
  do {                                                                     \
    size_t base = ((size_t)(w * 1024 + b * 256 + nb)) * 256;               \
    _Pragma("unroll") for (int s = 0; s < 4; ++s) {                        \
      pk[s] = skp4[base + s * 64 + l];                                     \
      pv[s] = svp4[base + s * 64 + l];                                     \
    }                                                                      \
  } while (0)

#define WRITEKV()                                                          \
  do {                                                                     \
    _Pragma("unroll") for (int s = 0; s < 4; ++s) {                        \
      int kk = s * 16 + (l >> 2);                                          \
      *(uint4*)(kbase + kk * 64 + sw * 16) = pk[s];                        \
      *(uint4*)(vbase + kk * 80 + (l & 3) * 16) = pv[s];                   \
    }                                                                      \
  } while (0)

  ISSUE();
  WRITEKV();

  f32x4 o[2][4];
  float ls[2][4];
#pragma unroll
  for (int hh = 0; hh < 2; ++hh)
#pragma unroll
    for (int qt = 0; qt < 4; ++qt) { o[hh][qt] = zf; ls[hh][qt] = 0.f; }

  for (int c = 0; c < 4; ++c) {  // ROLLED — do not unroll (spill trigger)
    if (c < 3) {
      nb = (c == 0) ? rn1 : (c == 1) ? rn2 : rn3;
      ISSUE();  // prefetch next chunk (no dependent route load)
    }
#pragma unroll
    for (int hh = 0; hh < 2; ++hh) {
      const int slotb = ((2 * hh + hi1) ^ xr) * 16;
      bf16x8 kf[4];
#pragma unroll
      for (int kt = 0; kt < 4; ++kt)
        kf[kt] = *(const bf16x8*)(kbase + (16 * kt + lo) * 64 + slotb);
#pragma unroll
      for (int kc = 0; kc < 2; ++kc) {
        f32x4 st0[4], st1[4];
#pragma unroll
        for (int qt = 0; qt < 4; ++qt) {
          st0[qt] = MFMA(kf[2 * kc], qf[hh][qt], zf);
          st1[qt] = MFMA(kf[2 * kc + 1], qf[hh][qt], zf);
        }
#pragma unroll
        for (int qt = 0; qt < 4; ++qt)
#pragma unroll
          for (int r = 0; r < 4; ++r) {
            float p0 = exp2f(st0[qt][r]);
            float p1 = exp2f(st1[qt][r]);
            st0[qt][r] = p0; st1[qt][r] = p1;
            ls[hh][qt] += p0 + p1;
          }
        // V fragments: 8 scalar u16 reads, [key][80B-stride] rows (2-way, free)
        bf16x8 vf;
#pragma unroll
        for (int i = 0; i < 8; ++i) {
          int key = 32 * kc + 16 * (i >> 2) + 4 * hi + (i & 3);
          vf[i] = *(const short*)(vbase + key * 80 + (hh * 16 + lo) * 2);
        }
#pragma unroll
        for (int qt = 0; qt < 4; ++qt) {
          bf16x8 pa;
#pragma unroll
          for (int r = 0; r < 4; ++r) {
            pa[r] = f2bfs(st0[qt][r]);
            pa[4 + r] = f2bfs(st1[qt][r]);
          }
          o[hh][qt] = MFMA(pa, vf, o[hh][qt]);
        }
      }
    }
    if (c < 3) WRITEKV();  // after compute(c): same-wave DS order, no barrier
  }

  // hoist at-fragments (global ot; no LDS dep) — latency hides under staging
  bf16x8 at[4];
#pragma unroll
  for (int kc = 0; kc < 4; ++kc)
    at[kc] = *(const bf16x8*)(ot + (size_t)bm * 8192 + (16 * w + lo) * 128 +
                              32 * kc + 8 * hi);

  // normalize + stage O_s [64 q][32 dim] into K region (stride 64; K dead)
#pragma unroll
  for (int hh = 0; hh < 2; ++hh)
#pragma unroll
    for (int qt = 0; qt < 4; ++qt) {
      float lsum = ls[hh][qt];
      lsum += __shfl_xor(lsum, 16);
      lsum += __shfl_xor(lsum, 32);
      float linv = 1.0f / lsum;
#pragma unroll
      for (int r = 0; r < 4; ++r) {
        float lr = __shfl(linv, 4 * hi + r);
        *(short*)(kbase + (16 * qt + 4 * hi + r) * 64 + (hh * 16 + lo) * 2) =
            f2bfs(o[hh][qt][r] * lr);
      }
    }
  __syncthreads();  // all waves staged

  // dual out-proj: accT from hoisted at, accS from staged O_s (LDS)
  f32x4 accT[8], accS[8];
#pragma unroll
  for (int ct = 0; ct < 8; ++ct) { accT[ct] = zf; accS[ct] = zf; }
#pragma unroll
  for (int kc = 0; kc < 4; ++kc) {
    bf16x8 as = *(const bf16x8*)(smem + kc * 9216 + (16 * w + lo) * 64 + hi * 16);
#pragma unroll
    for (int ct = 0; ct < 8; ++ct) {
      bf16x8 bt = *(const bf16x8*)(wto + (16 * ct + lo) * 128 + 32 * kc + 8 * hi);
      bf16x8 bs = *(const bf16x8*)(wso + (16 * ct + lo) * 128 + 32 * kc + 8 * hi);
      accT[ct] = MFMA(at[kc], bt, accT[ct]);
      accS[ct] = MFMA(as, bs, accS[ct]);
    }
  }
#pragma unroll
  for (int ct = 0; ct < 8; ++ct) {
    float bb = biasc[16 * ct + lo];
#pragma unroll
    for (int r = 0; r < 4; ++r) {
      int t = 16 * w + 4 * hi + r;
      out[(size_t)((b * 64 + t) * 256 + m) * 128 + 16 * ct + lo] =
          accT[ct][r] + accS[ct][r] + bb;
    }
  }
#undef ISSUE
#undef WRITEKV
}

// ---------------------------------------------------------------- launch ----
extern "C" void kernel_launch(void* const* d_in, const int* in_sizes, int n_in,
                              void* d_out, int out_size, void* d_ws, size_t ws_size,
                              hipStream_t stream) {
  (void)in_sizes; (void)n_in; (void)out_size; (void)ws_size;
  const float* x = (const float*)d_in[0];
  const int* route = (const int*)d_in[1];
  const float* twin = (const float*)d_in[2];
  const float* tbin = (const float*)d_in[3];
  const float* twout = (const float*)d_in[4];
  const float* tbout = (const float*)d_in[5];
  const float* swin = (const float*)d_in[6];
  const float* sbin = (const float*)d_in[7];
  const float* swout = (const float*)d_in[8];
  const float* sbout = (const float*)d_in[9];

  char* ws = (char*)d_ws;
  size_t off = 0;
  auto alloc = [&](size_t bytes) {
    char* p = ws + off;
    off += (bytes + 255) & ~(size_t)255;
    return p;
  };
  short* wcat = (short*)alloc(768 * 128 * 2);
  float* biasin = (float*)alloc(768 * 4);
  short* wto = (short*)alloc(128 * 128 * 2);
  short* wso = (short*)alloc(128 * 128 * 2);
  float* biasc = (float*)alloc(128 * 4);
  short* sq = (short*)alloc((size_t)65536 * 128 * 2);
  short* sk = (short*)alloc((size_t)65536 * 128 * 2);
  short* sv = (short*)alloc((size_t)65536 * 128 * 2);
  short* ot = (short*)alloc((size_t)65536 * 128 * 2);
  float* out = (float*)d_out;

  k_prep<<<dim3(64), dim3(256), 0, stream>>>(twin, tbin, twout, tbout, swin, sbin,
                                             swout, sbout, wcat, biasin, wto, wso, biasc);
  k_fused_t<<<dim3(1024), dim3(256), 0, stream>>>(x, wcat, biasin, sq, sk, sv,
                                                  (uint4*)ot);
  k_attn_s<<<dim3(1024), dim3(256), 0, stream>>>(sq, sk, sv, route, ot, wto, wso,
                                                 biasc, out);
}

// Round 19
// 195.323 us; speedup vs baseline: 1.3379x; 1.3379x over previous
//
#include <hip/hip_runtime.h>
#include <hip/hip_bf16.h>

// STSA R19 (final): R17 exactly + route[] hoist only.
// R18's launch_bounds(256,4) regression: allocator dropped VGPR 84->64 and
// spilled (FETCH/WRITE ~300/453MB scratch signature). This kernel's codegen
// is stable only at (256,3)/VGPR 84 — occupancy pressure tips it into scratch.
//  k_prep    : weights -> bf16.
//  k_fused_t : per (b,m): x->regs(af); s_q/s_k/s_v staged -> coalesced stores;
//              t_q/t_k/t_v -> LDS; temporal attn; normalized O_t -> ot.
//  k_attn_s  : 1024 blocks x 4 waves; wave = (bm, head-pair). Per-wave 9216B:
//              K [64 key][4x16B xor-slots] @0, V [64 key][80B rows] @4096.
//              4 neighbor-chunks, reg prefetch (route ids hoisted), ROLLED
//              chunk loop (unrolling triggers scratch spill), no mid-loop
//              barriers. Tail: hoist at-fragments, stage O_s into K region,
//              barrier, dual out-proj + bias -> direct out store.
// Softmax scale folded into Q (0.25*log2e*0.5; 0.5 compensates hd=16 dup
// into both K-halves), exp2, no max-subtract, normalize at the end.

typedef __attribute__((ext_vector_type(8))) short bf16x8;
typedef __attribute__((ext_vector_type(4))) short short4v;
typedef __attribute__((ext_vector_type(4))) float f32x4;

#define DEVI static __device__ __forceinline__
#define MFMA(a, b, c) __builtin_amdgcn_mfma_f32_16x16x32_bf16(a, b, c, 0, 0, 0)

static constexpr float QSCALE = 0.25f * 1.44269504088896340736f * 0.5f;

DEVI short f2bfs(float f) {
  __hip_bfloat16 h = __float2bfloat16(f);
  return __builtin_bit_cast(short, h);
}

// 64 rows x 128 bf16 LDS tile, 256B rows, XOR swizzle on write AND read.
DEVI int swzb(int row, int colh) {
  return (row * 256 + colh * 2) ^ ((row & 7) << 4);
}

// ---------------------------------------------------------------- k_prep ----
__global__ void __launch_bounds__(256) k_prep(
    const float* __restrict__ twin, const float* __restrict__ tbin,
    const float* __restrict__ twout, const float* __restrict__ tbout,
    const float* __restrict__ swin, const float* __restrict__ sbin,
    const float* __restrict__ swout, const float* __restrict__ sbout,
    short* __restrict__ wcat, float* __restrict__ biasin,
    short* __restrict__ wto, short* __restrict__ wso, float* __restrict__ biasc) {
  const int stride = gridDim.x * 256;
  const int t0 = blockIdx.x * 256 + threadIdx.x;
  for (int i = t0; i < 768 * 128; i += stride) {
    float v = (i < 384 * 128) ? twin[i] : swin[i - 384 * 128];
    wcat[i] = f2bfs(v);
  }
  for (int i = t0; i < 128 * 128; i += stride) {
    wto[i] = f2bfs(twout[i]);
    wso[i] = f2bfs(swout[i]);
  }
  for (int i = t0; i < 768; i += stride)
    biasin[i] = (i < 384) ? tbin[i] : sbin[i - 384];
  for (int i = t0; i < 128; i += stride)
    biasc[i] = tbout[i] + sbout[i];
}

// --------------------------------------------------------------- helpers ----
DEVI void attn_block(const char* qbuf, const char* kbuf, const char* vbuf,
                     int w, int lo, int hi, int colq,
                     f32x4 (*o)[4], float (*ls)[4]) {
  const f32x4 zf = {0.f, 0.f, 0.f, 0.f};
#pragma unroll
  for (int hh = 0; hh < 2; ++hh) {
    const int hc = (2 * w + hh) * 16;
    bf16x8 qf[4];
#pragma unroll
    for (int qt = 0; qt < 4; ++qt)
      qf[qt] = *(const bf16x8*)(qbuf + swzb(16 * qt + lo, hc + colq));
#pragma unroll
    for (int kc = 0; kc < 2; ++kc) {
      bf16x8 kf0 = *(const bf16x8*)(kbuf + swzb(16 * (2 * kc) + lo, hc + colq));
      bf16x8 kf1 = *(const bf16x8*)(kbuf + swzb(16 * (2 * kc + 1) + lo, hc + colq));
      f32x4 st0[4], st1[4];
#pragma unroll
      for (int qt = 0; qt < 4; ++qt) {
        st0[qt] = MFMA(kf0, qf[qt], zf);
        st1[qt] = MFMA(kf1, qf[qt], zf);
      }
#pragma unroll
      for (int qt = 0; qt < 4; ++qt)
#pragma unroll
        for (int r = 0; r < 4; ++r) {
          float p0 = exp2f(st0[qt][r]);
          float p1 = exp2f(st1[qt][r]);
          st0[qt][r] = p0; st1[qt][r] = p1;
          ls[hh][qt] += p0 + p1;
        }
      bf16x8 vf;
#pragma unroll
      for (int i = 0; i < 8; ++i) {
        int key = 32 * kc + 16 * (i >> 2) + 4 * hi + (i & 3);
        vf[i] = *(const short*)(vbuf + swzb(key, hc + lo));
      }
#pragma unroll
      for (int qt = 0; qt < 4; ++qt) {
        bf16x8 pa;
#pragma unroll
        for (int r = 0; r < 4; ++r) {
          pa[r] = f2bfs(st0[qt][r]);
          pa[4 + r] = f2bfs(st1[qt][r]);
        }
        o[hh][qt] = MFMA(pa, vf, o[hh][qt]);
      }
    }
  }
}

// -------------------------------------------------------------- k_fused_t ----
__global__ void __launch_bounds__(256) k_fused_t(
    const float* __restrict__ x, const short* __restrict__ wcat,
    const float* __restrict__ biasin,
    short* __restrict__ sq, short* __restrict__ sk, short* __restrict__ sv,
    uint4* __restrict__ ot) {
  __shared__ uint4 smv[3072];  // 48 KiB
  char* bufX = (char*)smv;     // x -> t_v
  char* bufQ = bufX + 16384;   // s-proj staging -> t_q -> O_t stage
  char* bufK = bufX + 32768;   // t_k
  const int bm = (blockIdx.x & 7) * 128 + (blockIdx.x >> 3);  // XCD-chunked
  const int b = bm >> 8, m = bm & 255;
  const int tid = threadIdx.x;

#pragma unroll
  for (int it = 0; it < 8; ++it) {
    int li = it * 256 + tid;
    int row = li >> 5, c4 = li & 31;
    float4 v = reinterpret_cast<const float4*>(x)[(size_t)((b * 64 + row) * 256 + m) * 32 + c4];
    short4v s;
    s[0] = f2bfs(v.x); s[1] = f2bfs(v.y); s[2] = f2bfs(v.z); s[3] = f2bfs(v.w);
    *(short4v*)(bufX + swzb(row, c4 * 4)) = s;
  }
  __syncthreads();

  const int w = tid >> 6, lane = tid & 63, lo = lane & 15, hi = lane >> 4;
  const int colq = 8 * (hi & 1);
  const f32x4 zf = {0.f, 0.f, 0.f, 0.f};

  bf16x8 af[4][4];
#pragma unroll
  for (int kc = 0; kc < 4; ++kc)
#pragma unroll
    for (int rt = 0; rt < 4; ++rt)
      af[kc][rt] = *(const bf16x8*)(bufX + swzb(16 * rt + lo, 32 * kc + 8 * hi));
  __syncthreads();

  // ---- s-projections FIRST (p = 3,4,5), staged through bufQ, coalesced store
#pragma unroll
  for (int p = 3; p < 6; ++p) {
#pragma unroll
    for (int j = 0; j < 2; ++j) {
      int ct = 2 * w + j;
      f32x4 a4[4] = {zf, zf, zf, zf};
#pragma unroll
      for (int kc = 0; kc < 4; ++kc) {
        bf16x8 bcol = *(const bf16x8*)(wcat + (p * 128 + 16 * ct + lo) * 128 + 32 * kc + 8 * hi);
#pragma unroll
        for (int rt = 0; rt < 4; ++rt) a4[rt] = MFMA(af[kc][rt], bcol, a4[rt]);
      }
      float bb = biasin[p * 128 + 16 * ct + lo];
      if (p == 3) {
#pragma unroll
        for (int rt = 0; rt < 4; ++rt)
#pragma unroll
          for (int r = 0; r < 4; ++r)
            *(short*)(bufQ + (16 * rt + 4 * hi + r) * 256 + (16 * ct + lo) * 2) =
                f2bfs((a4[rt][r] + bb) * QSCALE);
      } else {
        char* base = bufQ + (ct >> 1) * 4096;
        int qe = ((ct & 1) * 2 + (lo >> 3)) * 8 + (lo & 7);
#pragma unroll
        for (int rt = 0; rt < 4; ++rt)
#pragma unroll
          for (int r = 0; r < 4; ++r)
            *(short*)(base + (16 * rt + 4 * hi + r) * 64 + qe * 2) =
                f2bfs(a4[rt][r] + bb);
      }
    }
    __syncthreads();
    if (p == 3) {
#pragma unroll
      for (int it2 = 0; it2 < 4; ++it2) {
        int li = it2 * 256 + tid;
        ((uint4*)sq)[(size_t)bm * 1024 + li] = *(const uint4*)(bufQ + li * 16);
      }
    } else {
      short* dst = (p == 4) ? sk : sv;
#pragma unroll
      for (int wq = 0; wq < 4; ++wq)
        ((uint4*)dst)[((size_t)(wq * 1024 + bm)) * 256 + tid] =
            *(const uint4*)(bufQ + wq * 4096 + tid * 16);
    }
    __syncthreads();
  }

  // ---- t-projections (p = 0,1,2) -> LDS (swizzled)
#pragma unroll
  for (int p = 0; p < 3; ++p) {
#pragma unroll
    for (int j = 0; j < 2; ++j) {
      int ct = 2 * w + j;
      f32x4 a4[4] = {zf, zf, zf, zf};
#pragma unroll
      for (int kc = 0; kc < 4; ++kc) {
        bf16x8 bcol = *(const bf16x8*)(wcat + (p * 128 + 16 * ct + lo) * 128 + 32 * kc + 8 * hi);
#pragma unroll
        for (int rt = 0; rt < 4; ++rt) a4[rt] = MFMA(af[kc][rt], bcol, a4[rt]);
      }
      float bb = biasin[p * 128 + 16 * ct + lo];
      char* pb = (p == 0) ? bufQ : (p == 1) ? bufK : bufX;
      float sc = (p == 0) ? QSCALE : 1.0f;
#pragma unroll
      for (int rt = 0; rt < 4; ++rt)
#pragma unroll
        for (int r = 0; r < 4; ++r)
          *(short*)(pb + swzb(16 * rt + 4 * hi + r, 16 * ct + lo)) =
              f2bfs((a4[rt][r] + bb) * sc);
    }
  }
  __syncthreads();

  f32x4 o_t[2][4];
  float ls_t[2][4];
#pragma unroll
  for (int hh = 0; hh < 2; ++hh)
#pragma unroll
    for (int qt = 0; qt < 4; ++qt) { o_t[hh][qt] = zf; ls_t[hh][qt] = 0.f; }
  attn_block(bufQ, bufK, bufX, w, lo, hi, colq, o_t, ls_t);
  __syncthreads();

#pragma unroll
  for (int hh = 0; hh < 2; ++hh) {
    const int hc = (2 * w + hh) * 16;
#pragma unroll
    for (int qt = 0; qt < 4; ++qt) {
      float l = ls_t[hh][qt];
      l += __shfl_xor(l, 16);
      l += __shfl_xor(l, 32);
      float linv = 1.0f / l;
#pragma unroll
      for (int r = 0; r < 4; ++r) {
        float lr = __shfl(linv, 4 * hi + r);
        *(short*)(bufQ + swzb(16 * qt + 4 * hi + r, hc + lo)) = f2bfs(o_t[hh][qt][r] * lr);
      }
    }
  }
  __syncthreads();
#pragma unroll
  for (int it = 0; it < 4; ++it) {
    int li = it * 256 + tid;
    ot[(size_t)bm * 1024 + li] = *(const uint4*)(bufQ + swzb(li >> 4, (li & 15) * 8));
  }
}

// --------------------------------------------------------------- k_attn_s ----
// R17 structure (launch_bounds(256,3)) + hoisted route ids.
__global__ void __launch_bounds__(256, 3) k_attn_s(
    const short* __restrict__ sq, const short* __restrict__ skp,
    const short* __restrict__ svp, const int* __restrict__ route,
    const short* __restrict__ ot, const short* __restrict__ wto,
    const short* __restrict__ wso, const float* __restrict__ biasc,
    float* __restrict__ out) {
  __shared__ char smem[36864];  // 4 x 9216
  const int bm = (blockIdx.x & 7) * 128 + (blockIdx.x >> 3);  // XCD-chunked
  const int b = bm >> 8, m = bm & 255;
  const int tid = threadIdx.x;
  const int w = tid >> 6, l = tid & 63;
  const int lo = l & 15, hi = l >> 4, hi1 = hi & 1;
  const int xr = (l & 3) ^ ((l >> 2) & 3);             // reader xor (f(lo))
  const int sw = (l & 3) ^ ((l >> 2) & 3) ^ (l >> 4);  // writer slot q^xr(kk)
  char* kbase = smem + w * 9216;
  char* vbase = kbase + 4096;
  const uint4* skp4 = (const uint4*)skp;
  const uint4* svp4 = (const uint4*)svp;
  const f32x4 zf = {0.f, 0.f, 0.f, 0.f};

  // hoist neighbor ids: gather chains no longer wait on route loads
  const int rn0 = route[m * 4 + 0], rn1 = route[m * 4 + 1];
  const int rn2 = route[m * 4 + 2], rn3 = route[m * 4 + 3];

  // Q fragments (this head-pair's 32-dim slice), loaded once from global
  bf16x8 qf[2][4];
#pragma unroll
  for (int hh = 0; hh < 2; ++hh)
#pragma unroll
    for (int qt = 0; qt < 4; ++qt)
      qf[hh][qt] = *(const bf16x8*)(sq + (size_t)(bm * 64 + 16 * qt + lo) * 128 +
                                    w * 32 + hh * 16 + 8 * hi1);

  uint4 pk[4], pv[4];
  int nb = rn0;

#define ISSUE()                                                            \
  do {                                                                     \
    size_t base = ((size_t)(w * 1024 + b * 256 + nb)) * 256;               \
    _Pragma("unroll") for (int s = 0; s < 4; ++s) {                        \
      pk[s] = skp4[base + s * 64 + l];                                     \
      pv[s] = svp4[base + s * 64 + l];                                     \
    }                                                                      \
  } while (0)

#define WRITEKV()                                                          \
  do {                                                                     \
    _Pragma("unroll") for (int s = 0; s < 4; ++s) {                        \
      int kk = s * 16 + (l >> 2);                                          \
      *(uint4*)(kbase + kk * 64 + sw * 16) = pk[s];                        \
      *(uint4*)(vbase + kk * 80 + (l & 3) * 16) = pv[s];                   \
    }                                                                      \
  } while (0)

  ISSUE();
  WRITEKV();

  f32x4 o[2][4];
  float ls[2][4];
#pragma unroll
  for (int hh = 0; hh < 2; ++hh)
#pragma unroll
    for (int qt = 0; qt < 4; ++qt) { o[hh][qt] = zf; ls[hh][qt] = 0.f; }

  for (int c = 0; c < 4; ++c) {  // ROLLED — do not unroll (spill trigger)
    if (c < 3) {
      nb = (c == 0) ? rn1 : (c == 1) ? rn2 : rn3;
      ISSUE();  // prefetch next chunk (no dependent route load)
    }
#pragma unroll
    for (int hh = 0; hh < 2; ++hh) {
      const int slotb = ((2 * hh + hi1) ^ xr) * 16;
      bf16x8 kf[4];
#pragma unroll
      for (int kt = 0; kt < 4; ++kt)
        kf[kt] = *(const bf16x8*)(kbase + (16 * kt + lo) * 64 + slotb);
#pragma unroll
      for (int kc = 0; kc < 2; ++kc) {
        f32x4 st0[4], st1[4];
#pragma unroll
        for (int qt = 0; qt < 4; ++qt) {
          st0[qt] = MFMA(kf[2 * kc], qf[hh][qt], zf);
          st1[qt] = MFMA(kf[2 * kc + 1], qf[hh][qt], zf);
        }
#pragma unroll
        for (int qt = 0; qt < 4; ++qt)
#pragma unroll
          for (int r = 0; r < 4; ++r) {
            float p0 = exp2f(st0[qt][r]);
            float p1 = exp2f(st1[qt][r]);
            st0[qt][r] = p0; st1[qt][r] = p1;
            ls[hh][qt] += p0 + p1;
          }
        // V fragments: 8 scalar u16 reads, [key][80B-stride] rows (2-way, free)
        bf16x8 vf;
#pragma unroll
        for (int i = 0; i < 8; ++i) {
          int key = 32 * kc + 16 * (i >> 2) + 4 * hi + (i & 3);
          vf[i] = *(const short*)(vbase + key * 80 + (hh * 16 + lo) * 2);
        }
#pragma unroll
        for (int qt = 0; qt < 4; ++qt) {
          bf16x8 pa;
#pragma unroll
          for (int r = 0; r < 4; ++r) {
            pa[r] = f2bfs(st0[qt][r]);
            pa[4 + r] = f2bfs(st1[qt][r]);
          }
          o[hh][qt] = MFMA(pa, vf, o[hh][qt]);
        }
      }
    }
    if (c < 3) WRITEKV();  // after compute(c): same-wave DS order, no barrier
  }

  // hoist at-fragments (global ot; no LDS dep) — latency hides under staging
  bf16x8 at[4];
#pragma unroll
  for (int kc = 0; kc < 4; ++kc)
    at[kc] = *(const bf16x8*)(ot + (size_t)bm * 8192 + (16 * w + lo) * 128 +
                              32 * kc + 8 * hi);

  // normalize + stage O_s [64 q][32 dim] into K region (stride 64; K dead)
#pragma unroll
  for (int hh = 0; hh < 2; ++hh)
#pragma unroll
    for (int qt = 0; qt < 4; ++qt) {
      float lsum = ls[hh][qt];
      lsum += __shfl_xor(lsum, 16);
      lsum += __shfl_xor(lsum, 32);
      float linv = 1.0f / lsum;
#pragma unroll
      for (int r = 0; r < 4; ++r) {
        float lr = __shfl(linv, 4 * hi + r);
        *(short*)(kbase + (16 * qt + 4 * hi + r) * 64 + (hh * 16 + lo) * 2) =
            f2bfs(o[hh][qt][r] * lr);
      }
    }
  __syncthreads();  // all waves staged

  // dual out-proj: accT from hoisted at, accS from staged O_s (LDS)
  f32x4 accT[8], accS[8];
#pragma unroll
  for (int ct = 0; ct < 8; ++ct) { accT[ct] = zf; accS[ct] = zf; }
#pragma unroll
  for (int kc = 0; kc < 4; ++kc) {
    bf16x8 as = *(const bf16x8*)(smem + kc * 9216 + (16 * w + lo) * 64 + hi * 16);
#pragma unroll
    for (int ct = 0; ct < 8; ++ct) {
      bf16x8 bt = *(const bf16x8*)(wto + (16 * ct + lo) * 128 + 32 * kc + 8 * hi);
      bf16x8 bs = *(const bf16x8*)(wso + (16 * ct + lo) * 128 + 32 * kc + 8 * hi);
      accT[ct] = MFMA(at[kc], bt, accT[ct]);
      accS[ct] = MFMA(as, bs, accS[ct]);
    }
  }
#pragma unroll
  for (int ct = 0; ct < 8; ++ct) {
    float bb = biasc[16 * ct + lo];
#pragma unroll
    for (int r = 0; r < 4; ++r) {
      int t = 16 * w + 4 * hi + r;
      out[(size_t)((b * 64 + t) * 256 + m) * 128 + 16 * ct + lo] =
          accT[ct][r] + accS[ct][r] + bb;
    }
  }
#undef ISSUE
#undef WRITEKV
}

// ---------------------------------------------------------------- launch ----
extern "C" void kernel_launch(void* const* d_in, const int* in_sizes, int n_in,
                              void* d_out, int out_size, void* d_ws, size_t ws_size,
                              hipStream_t stream) {
  (void)in_sizes; (void)n_in; (void)out_size; (void)ws_size;
  const float* x = (const float*)d_in[0];
  const int* route = (const int*)d_in[1];
  const float* twin = (const float*)d_in[2];
  const float* tbin = (const float*)d_in[3];
  const float* twout = (const float*)d_in[4];
  const float* tbout = (const float*)d_in[5];
  const float* swin = (const float*)d_in[6];
  const float* sbin = (const float*)d_in[7];
  const float* swout = (const float*)d_in[8];
  const float* sbout = (const float*)d_in[9];

  char* ws = (char*)d_ws;
  size_t off = 0;
  auto alloc = [&](size_t bytes) {
    char* p = ws + off;
    off += (bytes + 255) & ~(size_t)255;
    return p;
  };
  short* wcat = (short*)alloc(768 * 128 * 2);
  float* biasin = (float*)alloc(768 * 4);
  short* wto = (short*)alloc(128 * 128 * 2);
  short* wso = (short*)alloc(128 * 128 * 2);
  float* biasc = (float*)alloc(128 * 4);
  short* sq = (short*)alloc((size_t)65536 * 128 * 2);
  short* sk = (short*)alloc((size_t)65536 * 128 * 2);
  short* sv = (short*)alloc((size_t)65536 * 128 * 2);
  short* ot = (short*)alloc((size_t)65536 * 128 * 2);
  float* out = (float*)d_out;

  k_prep<<<dim3(64), dim3(256), 0, stream>>>(twin, tbin, twout, tbout, swin, sbin,
                                             swout, sbout, wcat, biasin, wto, wso, biasc);
  k_fused_t<<<dim3(1024), dim3(256), 0, stream>>>(x, wcat, biasin, sq, sk, sv,
                                                  (uint4*)ot);
  k_attn_s<<<dim3(1024), dim3(256), 0, stream>>>(sq, sk, sv, route, ot, wto, wso,
                                                 biasc, out);
}

// Round 20
// 137.169 us; speedup vs baseline: 1.9051x; 1.4240x over previous
//
#include <hip/hip_runtime.h>
#include <hip/hip_bf16.h>

// STSA R20 = R14 verbatim (best measured: 137.3us). Restores after R18/R19
// codegen-spill regressions. Knife-edge note: k_attn_s compiles cleanly ONLY
// in this exact form — unrolling the chunk loop, launch_bounds(256,4), or even
// hoisting route[] into a select chain all tip the allocator into scratch
// (FETCH/WRITE 200-450MB spill signatures at R8-R10/R18/R19).
//  k_prep    : weights -> bf16.
//  k_fused_t : per (b,m): x->regs(af), 6 projections (t_q/t_k/t_v LDS,
//              s_q/s_k/s_v direct global stores), temporal attn -> ot (bf16).
//              sk/sv stored wave-slice-chunk-major: block (w'*1024+bm) of 4KB.
//  k_attn_s  : 1024 blocks x 4 waves; wave = (bm, head-pair). Per-wave 9216B:
//              K [64 key][4x16B xor-slots] @0, V [64 key][80B rows] @4096.
//              4 neighbor-chunks, reg prefetch, ROLLED chunk loop, no mid-loop
//              barriers. Tail: stage O_s into K region (stride 64), barrier,
//              dual out-proj (O_s LDS + O_t global) + bias -> out.
// Softmax scale folded into Q (0.25*log2e*0.5; 0.5 compensates hd=16 dup
// into both K-halves), exp2, no max-subtract, normalize at the end.

typedef __attribute__((ext_vector_type(8))) short bf16x8;
typedef __attribute__((ext_vector_type(4))) short short4v;
typedef __attribute__((ext_vector_type(4))) float f32x4;

#define DEVI static __device__ __forceinline__
#define MFMA(a, b, c) __builtin_amdgcn_mfma_f32_16x16x32_bf16(a, b, c, 0, 0, 0)

static constexpr float QSCALE = 0.25f * 1.44269504088896340736f * 0.5f;

DEVI short f2bfs(float f) {
  __hip_bfloat16 h = __float2bfloat16(f);
  return __builtin_bit_cast(short, h);
}

// 64 rows x 128 bf16 LDS tile, 256B rows, XOR swizzle on write AND read.
DEVI int swzb(int row, int colh) {
  return (row * 256 + colh * 2) ^ ((row & 7) << 4);
}

// ---------------------------------------------------------------- k_prep ----
__global__ void __launch_bounds__(256) k_prep(
    const float* __restrict__ twin, const float* __restrict__ tbin,
    const float* __restrict__ twout, const float* __restrict__ tbout,
    const float* __restrict__ swin, const float* __restrict__ sbin,
    const float* __restrict__ swout, const float* __restrict__ sbout,
    short* __restrict__ wcat, float* __restrict__ biasin,
    short* __restrict__ wto, short* __restrict__ wso, float* __restrict__ biasc) {
  const int stride = gridDim.x * 256;
  const int t0 = blockIdx.x * 256 + threadIdx.x;
  for (int i = t0; i < 768 * 128; i += stride) {
    float v = (i < 384 * 128) ? twin[i] : swin[i - 384 * 128];
    wcat[i] = f2bfs(v);
  }
  for (int i = t0; i < 128 * 128; i += stride) {
    wto[i] = f2bfs(twout[i]);
    wso[i] = f2bfs(swout[i]);
  }
  for (int i = t0; i < 768; i += stride)
    biasin[i] = (i < 384) ? tbin[i] : sbin[i - 384];
  for (int i = t0; i < 128; i += stride)
    biasc[i] = tbout[i] + sbout[i];
}

// --------------------------------------------------------------- helpers ----
DEVI void attn_block(const char* qbuf, const char* kbuf, const char* vbuf,
                     int w, int lo, int hi, int colq,
                     f32x4 (*o)[4], float (*ls)[4]) {
  const f32x4 zf = {0.f, 0.f, 0.f, 0.f};
#pragma unroll
  for (int hh = 0; hh < 2; ++hh) {
    const int hc = (2 * w + hh) * 16;
    bf16x8 qf[4];
#pragma unroll
    for (int qt = 0; qt < 4; ++qt)
      qf[qt] = *(const bf16x8*)(qbuf + swzb(16 * qt + lo, hc + colq));
#pragma unroll
    for (int kc = 0; kc < 2; ++kc) {
      bf16x8 kf0 = *(const bf16x8*)(kbuf + swzb(16 * (2 * kc) + lo, hc + colq));
      bf16x8 kf1 = *(const bf16x8*)(kbuf + swzb(16 * (2 * kc + 1) + lo, hc + colq));
      f32x4 st0[4], st1[4];
#pragma unroll
      for (int qt = 0; qt < 4; ++qt) {
        st0[qt] = MFMA(kf0, qf[qt], zf);
        st1[qt] = MFMA(kf1, qf[qt], zf);
      }
#pragma unroll
      for (int qt = 0; qt < 4; ++qt)
#pragma unroll
        for (int r = 0; r < 4; ++r) {
          float p0 = exp2f(st0[qt][r]);
          float p1 = exp2f(st1[qt][r]);
          st0[qt][r] = p0; st1[qt][r] = p1;
          ls[hh][qt] += p0 + p1;
        }
      bf16x8 vf;
#pragma unroll
      for (int i = 0; i < 8; ++i) {
        int key = 32 * kc + 16 * (i >> 2) + 4 * hi + (i & 3);
        vf[i] = *(const short*)(vbuf + swzb(key, hc + lo));
      }
#pragma unroll
      for (int qt = 0; qt < 4; ++qt) {
        bf16x8 pa;
#pragma unroll
        for (int r = 0; r < 4; ++r) {
          pa[r] = f2bfs(st0[qt][r]);
          pa[4 + r] = f2bfs(st1[qt][r]);
        }
        o[hh][qt] = MFMA(pa, vf, o[hh][qt]);
      }
    }
  }
}

// -------------------------------------------------------------- k_fused_t ----
__global__ void __launch_bounds__(256) k_fused_t(
    const float* __restrict__ x, const short* __restrict__ wcat,
    const float* __restrict__ biasin,
    short* __restrict__ sq, short* __restrict__ sk, short* __restrict__ sv,
    uint4* __restrict__ ot) {
  __shared__ uint4 smv[3072];  // 48 KiB
  char* bufX = (char*)smv;     // x -> t_v
  char* bufQ = bufX + 16384;   // t_q -> O_t stage
  char* bufK = bufX + 32768;   // t_k
  const int bm = blockIdx.x, b = bm >> 8, m = bm & 255;
  const int tid = threadIdx.x;

#pragma unroll
  for (int it = 0; it < 8; ++it) {
    int li = it * 256 + tid;
    int row = li >> 5, c4 = li & 31;
    float4 v = reinterpret_cast<const float4*>(x)[(size_t)((b * 64 + row) * 256 + m) * 32 + c4];
    short4v s;
    s[0] = f2bfs(v.x); s[1] = f2bfs(v.y); s[2] = f2bfs(v.z); s[3] = f2bfs(v.w);
    *(short4v*)(bufX + swzb(row, c4 * 4)) = s;
  }
  __syncthreads();

  const int w = tid >> 6, lane = tid & 63, lo = lane & 15, hi = lane >> 4;
  const int colq = 8 * (hi & 1);
  const f32x4 zf = {0.f, 0.f, 0.f, 0.f};

  bf16x8 af[4][4];
#pragma unroll
  for (int kc = 0; kc < 4; ++kc)
#pragma unroll
    for (int rt = 0; rt < 4; ++rt)
      af[kc][rt] = *(const bf16x8*)(bufX + swzb(16 * rt + lo, 32 * kc + 8 * hi));
  __syncthreads();

#pragma unroll
  for (int p = 0; p < 6; ++p) {
#pragma unroll
    for (int j = 0; j < 2; ++j) {
      int ct = 2 * w + j;
      f32x4 a4[4] = {zf, zf, zf, zf};
#pragma unroll
      for (int kc = 0; kc < 4; ++kc) {
        bf16x8 bcol = *(const bf16x8*)(wcat + (p * 128 + 16 * ct + lo) * 128 + 32 * kc + 8 * hi);
#pragma unroll
        for (int rt = 0; rt < 4; ++rt) a4[rt] = MFMA(af[kc][rt], bcol, a4[rt]);
      }
      float bb = biasin[p * 128 + 16 * ct + lo];
      if (p < 3) {
        char* pb = (p == 0) ? bufQ : (p == 1) ? bufK : bufX;
        float sc = (p == 0) ? QSCALE : 1.0f;
#pragma unroll
        for (int rt = 0; rt < 4; ++rt)
#pragma unroll
          for (int r = 0; r < 4; ++r)
            *(short*)(pb + swzb(16 * rt + 4 * hi + r, 16 * ct + lo)) =
                f2bfs((a4[rt][r] + bb) * sc);
      } else if (p == 3) {
#pragma unroll
        for (int rt = 0; rt < 4; ++rt)
#pragma unroll
          for (int r = 0; r < 4; ++r)
            sq[(size_t)(bm * 64 + 16 * rt + 4 * hi + r) * 128 + 16 * ct + lo] =
                f2bfs((a4[rt][r] + bb) * QSCALE);
      } else {
        // sk/sv wave-slice-chunk-major: block (w'*1024+bm), w' = ct>>1
        short* dst = (p == 4) ? sk : sv;
        size_t blk = ((size_t)((ct >> 1) * 1024 + bm)) * 2048;
        int qe = ((ct & 1) * 2 + (lo >> 3)) * 8 + (lo & 7);
#pragma unroll
        for (int rt = 0; rt < 4; ++rt)
#pragma unroll
          for (int r = 0; r < 4; ++r)
            dst[blk + (16 * rt + 4 * hi + r) * 32 + qe] = f2bfs(a4[rt][r] + bb);
      }
    }
  }
  __syncthreads();

  f32x4 o_t[2][4];
  float ls_t[2][4];
#pragma unroll
  for (int hh = 0; hh < 2; ++hh)
#pragma unroll
    for (int qt = 0; qt < 4; ++qt) { o_t[hh][qt] = zf; ls_t[hh][qt] = 0.f; }
  attn_block(bufQ, bufK, bufX, w, lo, hi, colq, o_t, ls_t);
  __syncthreads();

#pragma unroll
  for (int hh = 0; hh < 2; ++hh) {
    const int hc = (2 * w + hh) * 16;
#pragma unroll
    for (int qt = 0; qt < 4; ++qt) {
      float l = ls_t[hh][qt];
      l += __shfl_xor(l, 16);
      l += __shfl_xor(l, 32);
      float linv = 1.0f / l;
#pragma unroll
      for (int r = 0; r < 4; ++r) {
        float lr = __shfl(linv, 4 * hi + r);
        *(short*)(bufQ + swzb(16 * qt + 4 * hi + r, hc + lo)) = f2bfs(o_t[hh][qt][r] * lr);
      }
    }
  }
  __syncthreads();
#pragma unroll
  for (int it = 0; it < 4; ++it) {
    int li = it * 256 + tid;
    ot[(size_t)bm * 1024 + li] = *(const uint4*)(bufQ + swzb(li >> 4, (li & 15) * 8));
  }
}

// --------------------------------------------------------------- k_attn_s ----
// Wave w of block bm = head-pair w (dims w*32..w*32+32). Per-wave 9216B region:
//   K @0    : [64 key][4 x 16B slots], write slot = (l&3)^((l>>2)&3)^(l>>4),
//             read slot = ((2hh+hi1) ^ xr(row)), xr(row)=(row&3)^((row>>2)&3)
//   V @4096 : [64 key][80B-stride rows]; 16B-aligned uint4 writes, u16 reads
// ISSUE: 4 x 1KB contiguous loads from wave-sliced sk/sv blocks; lane l load s
// holds quarter q=l&3 of key kk=s*16+(l>>2). Chunk loop ROLLED (spill guard).
// Tail: stage O_s into K region (stride 64, 16B-aligned reads), barrier,
// dual out-proj (O_s from LDS, O_t from global ot) + bias -> out.
__global__ void __launch_bounds__(256, 3) k_attn_s(
    const short* __restrict__ sq, const short* __restrict__ skp,
    const short* __restrict__ svp, const int* __restrict__ route,
    const short* __restrict__ ot, const short* __restrict__ wto,
    const short* __restrict__ wso, const float* __restrict__ biasc,
    float* __restrict__ out) {
  __shared__ char smem[36864];  // 4 x 9216
  const int bm = blockIdx.x, b = bm >> 8, m = bm & 255;
  const int tid = threadIdx.x;
  const int w = tid >> 6, l = tid & 63;
  const int lo = l & 15, hi = l >> 4, hi1 = hi & 1;
  const int xr = (l & 3) ^ ((l >> 2) & 3);             // reader xor (f(lo))
  const int sw = (l & 3) ^ ((l >> 2) & 3) ^ (l >> 4);  // writer slot q^xr(kk)
  char* kbase = smem + w * 9216;
  char* vbase = kbase + 4096;
  const uint4* skp4 = (const uint4*)skp;
  const uint4* svp4 = (const uint4*)svp;
  const f32x4 zf = {0.f, 0.f, 0.f, 0.f};

  // Q fragments (this head-pair's 32-dim slice), loaded once from global
  bf16x8 qf[2][4];
#pragma unroll
  for (int hh = 0; hh < 2; ++hh)
#pragma unroll
    for (int qt = 0; qt < 4; ++qt)
      qf[hh][qt] = *(const bf16x8*)(sq + (size_t)(bm * 64 + 16 * qt + lo) * 128 +
                                    w * 32 + hh * 16 + 8 * hi1);

  uint4 pk[4], pv[4];
  int nb = route[m * 4 + 0];

#define ISSUE()                                                            \
  do {                                                                     \
    size_t base = ((size_t)(w * 1024 + b * 256 + nb)) * 256;               \
    _Pragma("unroll") for (int s = 0; s < 4; ++s) {                        \
      pk[s] = skp4[base + s * 64 + l];                                     \
      pv[s] = svp4[base + s * 64 + l];                                     \
    }                                                                      \
  } while (0)

#define WRITEKV()                                                          \
  do {                                                                     \
    _Pragma("unroll") for (int s = 0; s < 4; ++s) {                        \
      int kk = s * 16 + (l >> 2);                                          \
      *(uint4*)(kbase + kk * 64 + sw * 16) = pk[s];                        \
      *(uint4*)(vbase + kk * 80 + (l & 3) * 16) = pv[s];                   \
    }                                                                      \
  } while (0)

  ISSUE();
  WRITEKV();

  f32x4 o[2][4];
  float ls[2][4];
#pragma unroll
  for (int hh = 0; hh < 2; ++hh)
#pragma unroll
    for (int qt = 0; qt < 4; ++qt) { o[hh][qt] = zf; ls[hh][qt] = 0.f; }

  for (int c = 0; c < 4; ++c) {  // ROLLED — do not unroll (spill trigger)
    if (c < 3) { nb = route[m * 4 + c + 1]; ISSUE(); }  // prefetch next chunk
#pragma unroll
    for (int hh = 0; hh < 2; ++hh) {
      const int slotb = ((2 * hh + hi1) ^ xr) * 16;
      bf16x8 kf[4];
#pragma unroll
      for (int kt = 0; kt < 4; ++kt)
        kf[kt] = *(const bf16x8*)(kbase + (16 * kt + lo) * 64 + slotb);
#pragma unroll
      for (int kc = 0; kc < 2; ++kc) {
        f32x4 st0[4], st1[4];
#pragma unroll
        for (int qt = 0; qt < 4; ++qt) {
          st0[qt] = MFMA(kf[2 * kc], qf[hh][qt], zf);
          st1[qt] = MFMA(kf[2 * kc + 1], qf[hh][qt], zf);
        }
#pragma unroll
        for (int qt = 0; qt < 4; ++qt)
#pragma unroll
          for (int r = 0; r < 4; ++r) {
            float p0 = exp2f(st0[qt][r]);
            float p1 = exp2f(st1[qt][r]);
            st0[qt][r] = p0; st1[qt][r] = p1;
            ls[hh][qt] += p0 + p1;
          }
        // V fragments: 8 scalar u16 reads, [key][80B-stride] rows (2-way, free)
        bf16x8 vf;
#pragma unroll
        for (int i = 0; i < 8; ++i) {
          int key = 32 * kc + 16 * (i >> 2) + 4 * hi + (i & 3);
          vf[i] = *(const short*)(vbase + key * 80 + (hh * 16 + lo) * 2);
        }
#pragma unroll
        for (int qt = 0; qt < 4; ++qt) {
          bf16x8 pa;
#pragma unroll
          for (int r = 0; r < 4; ++r) {
            pa[r] = f2bfs(st0[qt][r]);
            pa[4 + r] = f2bfs(st1[qt][r]);
          }
          o[hh][qt] = MFMA(pa, vf, o[hh][qt]);
        }
      }
    }
    if (c < 3) WRITEKV();  // after compute(c): same-wave DS order, no barrier
  }

  // normalize + stage O_s [64 q][32 dim] into K region (stride 64; K dead)
#pragma unroll
  for (int hh = 0; hh < 2; ++hh)
#pragma unroll
    for (int qt = 0; qt < 4; ++qt) {
      float lsum = ls[hh][qt];
      lsum += __shfl_xor(lsum, 16);
      lsum += __shfl_xor(lsum, 32);
      float linv = 1.0f / lsum;
#pragma unroll
      for (int r = 0; r < 4; ++r) {
        float lr = __shfl(linv, 4 * hi + r);
        *(short*)(kbase + (16 * qt + 4 * hi + r) * 64 + (hh * 16 + lo) * 2) =
            f2bfs(o[hh][qt][r] * lr);
      }
    }
  __syncthreads();  // all waves staged

  // dual out-proj: accT from global ot fragments, accS from staged O_s (LDS)
  f32x4 accT[8], accS[8];
#pragma unroll
  for (int ct = 0; ct < 8; ++ct) { accT[ct] = zf; accS[ct] = zf; }
#pragma unroll
  for (int kc = 0; kc < 4; ++kc) {
    bf16x8 as = *(const bf16x8*)(smem + kc * 9216 + (16 * w + lo) * 64 + hi * 16);
    bf16x8 at = *(const bf16x8*)(ot + (size_t)bm * 8192 + (16 * w + lo) * 128 +
                                 32 * kc + 8 * hi);
#pragma unroll
    for (int ct = 0; ct < 8; ++ct) {
      bf16x8 bt = *(const bf16x8*)(wto + (16 * ct + lo) * 128 + 32 * kc + 8 * hi);
      bf16x8 bs = *(const bf16x8*)(wso + (16 * ct + lo) * 128 + 32 * kc + 8 * hi);
      accT[ct] = MFMA(at, bt, accT[ct]);
      accS[ct] = MFMA(as, bs, accS[ct]);
    }
  }
#pragma unroll
  for (int ct = 0; ct < 8; ++ct) {
    float bb = biasc[16 * ct + lo];
#pragma unroll
    for (int r = 0; r < 4; ++r) {
      int t = 16 * w + 4 * hi + r;
      out[(size_t)((b * 64 + t) * 256 + m) * 128 + 16 * ct + lo] =
          accT[ct][r] + accS[ct][r] + bb;
    }
  }
#undef ISSUE
#undef WRITEKV
}

// ---------------------------------------------------------------- launch ----
extern "C" void kernel_launch(void* const* d_in, const int* in_sizes, int n_in,
                              void* d_out, int out_size, void* d_ws, size_t ws_size,
                              hipStream_t stream) {
  (void)in_sizes; (void)n_in; (void)out_size; (void)ws_size;
  const float* x = (const float*)d_in[0];
  const int* route = (const int*)d_in[1];
  const float* twin = (const float*)d_in[2];
  const float* tbin = (const float*)d_in[3];
  const float* twout = (const float*)d_in[4];
  const float* tbout = (const float*)d_in[5];
  const float* swin = (const float*)d_in[6];
  const float* sbin = (const float*)d_in[7];
  const float* swout = (const float*)d_in[8];
  const float* sbout = (const float*)d_in[9];

  char* ws = (char*)d_ws;
  size_t off = 0;
  auto alloc = [&](size_t bytes) {
    char* p = ws + off;
    off += (bytes + 255) & ~(size_t)255;
    return p;
  };
  short* wcat = (short*)alloc(768 * 128 * 2);
  float* biasin = (float*)alloc(768 * 4);
  short* wto = (short*)alloc(128 * 128 * 2);
  short* wso = (short*)alloc(128 * 128 * 2);
  float* biasc = (float*)alloc(128 * 4);
  short* sq = (short*)alloc((size_t)65536 * 128 * 2);
  short* sk = (short*)alloc((size_t)65536 * 128 * 2);
  short* sv = (short*)alloc((size_t)65536 * 128 * 2);
  short* ot = (short*)alloc((size_t)65536 * 128 * 2);
  float* out = (float*)d_out;

  k_prep<<<dim3(64), dim3(256), 0, stream>>>(twin, tbin, twout, tbout, swin, sbin,
                                             swout, sbout, wcat, biasin, wto, wso, biasc);
  k_fused_t<<<dim3(1024), dim3(256), 0, stream>>>(x, wcat, biasin, sq, sk, sv,
                                                  (uint4*)ot);
  k_attn_s<<<dim3(1024), dim3(256), 0, stream>>>(sq, sk, sv, route, ot, wto, wso,
                                                 biasc, out);
}